// Round 5
// baseline (621.901 us; speedup 1.0000x reference)
//
#include <hip/hip_runtime.h>
#include <hip/hip_bf16.h>
#include <cstdint>

// KAN MLP: 256->512->512->256, B=8192, cubic B-splines (uniform grid h=0.25,
// knots -1.75..1.75, 11 bases), BN at the end.
//
// Round-5: expansion FUSED into the GEMM (redundancy x4/x2, no atomics).
// Per layer, one kernel: reads h (or X) fp32, expands [gelu|11 bases] in
// registers (pipelined one slab ahead), stages A via ds_write_b128 into a
// 16-feature (192-k = 3 BK-chunk) LDS slab, B via register prefetch +
// ds_write_b128, MFMA 128x128 tile / BK=64 (round-4 verified fragment maps).
// Split-K partial buffers; reduction fused into consumer (next layer / BN).
//
// LDS: As 128 rows x 24 chunks x 16B = 48 KB (XOR cs=kc^(m&7), 2-way-free),
//      Bs 128 rows x 8 chunks x 16B = 16 KB (round-4 layout, measured 0
//      conflicts). Total exactly 64 KB -> 2 blocks/CU.
//
// Workspace (<= 113,246,208 B):
//   W0 @ 0          : 3,145,728
//   W1 @ 3145728    : 6,291,456
//   W2 @ 9437184    : 3,145,728
//   P  @ 12582912   : 2 x 16 MB fp32 (L0 out partials)
//   R  @ 46137344   : 2 x 16 MB fp32 (L1 out partials)
//   Q  @ 79691776   : 4 x  8 MB fp32 (L2 out partials)

typedef unsigned short ushort_t;
typedef __bf16 bf16x8 __attribute__((ext_vector_type(8)));
typedef float f32x4 __attribute__((ext_vector_type(4)));

__device__ __forceinline__ ushort_t f2bf(float f) {
    __bf16 h = (__bf16)f;  // RNE
    return __builtin_bit_cast(ushort_t, h);
}

// x -> [gelu, b0..b10] (12 bf16). Direct cardinal cubic B-spline (verified
// rounds 3-4, absmax 0.0078): b(t), a=|t-2|: a<=1: (4-6a^2+3a^3)/6;
// 1<a<2: (2-a)^3/6; else 0.
__device__ __forceinline__ void expand12(float x, ushort_t* o) {
    float x3 = x * x * x;
    float y  = 0.7978845608028654f * (x + 0.044715f * x3);
    float e  = __expf(2.0f * y);
    float th = 1.0f - 2.0f / (e + 1.0f);       // tanh(y)
    o[0] = f2bf(0.5f * x * (1.0f + th));
    float xs = (x + 1.75f) * 4.0f;
#pragma unroll
    for (int j = 0; j < 11; ++j) {
        float t  = xs - (float)j;
        float a  = fabsf(t - 2.0f);
        float p1 = (3.0f * a - 6.0f) * a * a + 4.0f;
        float c  = 2.0f - a;
        float p2 = c * c * c;
        float v  = (a <= 1.0f) ? p1 : fmaxf(p2, 0.0f);
        o[1 + j] = f2bf(v * (1.0f / 6.0f));
    }
}

__device__ __forceinline__ void expand_pair(float hx, float hy, uint4* ev) {
    union { ushort_t us[24]; uint4 v[3]; } pk;
    expand12(hx, pk.us);
    expand12(hy, pk.us + 12);
    ev[0] = pk.v[0]; ev[1] = pk.v[1]; ev[2] = pk.v[2];
}

// ---------------------------------------------------------------------------
// Fused weight pack (all 3 layers in one dispatch). Row-major W[o][k] bf16,
// k = i*12 + comp (comp 0 = base, 1..11 = spline).
// ---------------------------------------------------------------------------
__global__ __launch_bounds__(256) void pack_all_kernel(
    const float* __restrict__ bw0, const float* __restrict__ sw0, ushort_t* __restrict__ W0,
    const float* __restrict__ bw1, const float* __restrict__ sw1, ushort_t* __restrict__ W1,
    const float* __restrict__ bw2, const float* __restrict__ sw2, ushort_t* __restrict__ W2)
{
    int idx = blockIdx.x * 256 + threadIdx.x;
    const float* bw; const float* sw; ushort_t* W; int local;
    if (idx < 131072)      { bw = bw0; sw = sw0; W = W0; local = idx; }
    else if (idx < 393216) { bw = bw1; sw = sw1; W = W1; local = idx - 131072; }
    else                   { bw = bw2; sw = sw2; W = W2; local = idx - 393216; }
    union { ushort_t us[12]; uint2 v[3]; } pk;
    pk.us[0] = f2bf(bw[local]);
    const float* s = sw + (size_t)local * 11;
#pragma unroll
    for (int k = 0; k < 11; ++k) pk.us[1 + k] = f2bf(s[k]);
    uint2* dst = (uint2*)(W + (size_t)local * 12);
    dst[0] = pk.v[0]; dst[1] = pk.v[1]; dst[2] = pk.v[2];
}

// ---------------------------------------------------------------------------
// Fused KAN GEMM. C_z[M,N] = expand(X)[M, kslice] @ W[N, kslice]^T.
// Tile 128x128, BK=64, slab = 3 BK (16 features). 4 waves 2x2, wave 64x64.
//   A frag: lane holds A[m=l15][k=q*8+j]; C/D: D[m=q*4+r][n=l15].
// SUM: X := X0 + X0[xoff] (previous layer's split-K pair reduced on the fly).
// ---------------------------------------------------------------------------
template <bool SUM>
__global__ __launch_bounds__(256, 2) void kan_gemm_kernel(
    const float* __restrict__ X0, const ushort_t* __restrict__ Wm,
    float* __restrict__ C, int M, int fin, int N, int spl, size_t xoff)
{
    __shared__ __align__(16) ushort_t As[128 * 24 * 8];  // 48 KB
    __shared__ __align__(16) ushort_t Bs[128 * 8 * 8];   // 16 KB

    const int t   = threadIdx.x;
    const int l   = t & 63;
    const int w   = t >> 6;
    const int wmm = w >> 1;
    const int wn  = w & 1;
    const int l15 = l & 15;
    const int q   = l >> 4;
    const int K   = fin * 12;
    const int blockM = blockIdx.x * 128;
    const int blockN = blockIdx.y * 128;
    const int z   = blockIdx.z;
    const int slab0 = z * spl;
    const int xr  = t >> 3;   // 0..31 (expansion row group)
    const int fp  = t & 7;    // feature-pair within slab

    f32x4 acc[4][4];
#pragma unroll
    for (int i = 0; i < 4; ++i)
#pragma unroll
        for (int j = 0; j < 4; ++j) acc[i][j] = (f32x4){0.f, 0.f, 0.f, 0.f};

    // B staging pointers: slot s = it*256+t -> row=it*32+xr, chunk g=fp^(row&7)
    const ushort_t* wp[4];
#pragma unroll
    for (int it = 0; it < 4; ++it) {
        int row = it * 32 + xr;
        int g   = fp ^ (row & 7);
        wp[it] = Wm + (size_t)(blockN + row) * K + g * 8;
    }
    // X pointers (row = blockM + i*32 + xr, feature base fp*2)
    const float* xp[4];
#pragma unroll
    for (int i = 0; i < 4; ++i)
        xp[i] = X0 + (size_t)(blockM + i * 32 + xr) * fin + fp * 2;

    uint4  breg[4];
    float2 xa[4];
    uint4  ereg[4][3];

    // prologue: B(kb0), X(slab0) -> expand -> prefetch X(slab0+1)
#pragma unroll
    for (int it = 0; it < 4; ++it)
        breg[it] = *(const uint4*)(wp[it] + (size_t)(slab0 * 3) * 64);
#pragma unroll
    for (int i = 0; i < 4; ++i) {
        xa[i] = *(const float2*)(xp[i] + (size_t)slab0 * 16);
        if (SUM) {
            float2 b = *(const float2*)(xp[i] + xoff + (size_t)slab0 * 16);
            xa[i].x += b.x; xa[i].y += b.y;
        }
    }
#pragma unroll
    for (int i = 0; i < 4; ++i) expand_pair(xa[i].x, xa[i].y, ereg[i]);
    {
        int ns = (spl > 1) ? (slab0 + 1) : slab0;
#pragma unroll
        for (int i = 0; i < 4; ++i) {
            xa[i] = *(const float2*)(xp[i] + (size_t)ns * 16);
            if (SUM) {
                float2 b = *(const float2*)(xp[i] + xoff + (size_t)ns * 16);
                xa[i].x += b.x; xa[i].y += b.y;
            }
        }
    }

#define MFMA_BLOCK(KB)                                                         \
    {                                                                          \
        _Pragma("unroll")                                                      \
        for (int ks = 0; ks < 2; ++ks) {                                       \
            const int kc  = (KB) * 8 + ks * 4 + q;                             \
            const int kc8 = ks * 4 + q;                                        \
            bf16x8 af[4], bfr[4];                                              \
            _Pragma("unroll")                                                  \
            for (int mi = 0; mi < 4; ++mi) {                                   \
                int m  = wmm * 64 + mi * 16 + l15;                             \
                int cs = kc ^ (m & 7);                                         \
                af[mi] = *(const bf16x8*)&As[(size_t)(m * 24 + cs) * 8];       \
            }                                                                  \
            _Pragma("unroll")                                                  \
            for (int ni = 0; ni < 4; ++ni) {                                   \
                int n  = wn * 64 + ni * 16 + l15;                              \
                int cs = kc8 ^ (n & 7);                                        \
                bfr[ni] = *(const bf16x8*)&Bs[(size_t)(n * 8 + cs) * 8];       \
            }                                                                  \
            _Pragma("unroll")                                                  \
            for (int mi = 0; mi < 4; ++mi)                                     \
                _Pragma("unroll")                                              \
                for (int ni = 0; ni < 4; ++ni)                                 \
                    acc[mi][ni] = __builtin_amdgcn_mfma_f32_16x16x32_bf16(     \
                        af[mi], bfr[ni], acc[mi][ni], 0, 0, 0);                \
        }                                                                      \
    }

    for (int sl = 0; sl < spl; ++sl) {
        const int kbg = (slab0 + sl) * 3;
        __syncthreads();  // previous slab's readers done
        // A slab: 12 ds_write_b128, cs = (fp*3+j)^(m&7) -> 2-way free
#pragma unroll
        for (int i = 0; i < 4; ++i) {
            int m = i * 32 + xr;
#pragma unroll
            for (int j = 0; j < 3; ++j) {
                int cs = (fp * 3 + j) ^ (m & 7);
                *(uint4*)&As[(size_t)(m * 24 + cs) * 8] = ereg[i][j];
            }
        }
        // B kb0: linear slots, 2-way free
#pragma unroll
        for (int it = 0; it < 4; ++it) ((uint4*)Bs)[it * 256 + t] = breg[it];
        __syncthreads();

#pragma unroll
        for (int it = 0; it < 4; ++it)
            breg[it] = *(const uint4*)(wp[it] + (size_t)(kbg + 1) * 64);
        MFMA_BLOCK(0)

        // pipelined expansion for next slab (VALU overlaps MFMA issue)
        if (sl + 1 < spl) {
#pragma unroll
            for (int i = 0; i < 4; ++i) expand_pair(xa[i].x, xa[i].y, ereg[i]);
            int ns = (sl + 2 < spl) ? (slab0 + sl + 2) : (slab0 + spl - 1);
#pragma unroll
            for (int i = 0; i < 4; ++i) {
                xa[i] = *(const float2*)(xp[i] + (size_t)ns * 16);
                if (SUM) {
                    float2 b = *(const float2*)(xp[i] + xoff + (size_t)ns * 16);
                    xa[i].x += b.x; xa[i].y += b.y;
                }
            }
        }
        __syncthreads();  // kb0 B readers done
#pragma unroll
        for (int it = 0; it < 4; ++it) ((uint4*)Bs)[it * 256 + t] = breg[it];
        __syncthreads();
#pragma unroll
        for (int it = 0; it < 4; ++it)
            breg[it] = *(const uint4*)(wp[it] + (size_t)(kbg + 2) * 64);
        MFMA_BLOCK(1)
        __syncthreads();  // kb1 B readers done
#pragma unroll
        for (int it = 0; it < 4; ++it) ((uint4*)Bs)[it * 256 + t] = breg[it];
        __syncthreads();
        {
            int nkb = (sl + 1 < spl) ? (kbg + 3) : (kbg + 2);
#pragma unroll
            for (int it = 0; it < 4; ++it)
                breg[it] = *(const uint4*)(wp[it] + (size_t)nkb * 64);
        }
        MFMA_BLOCK(2)
    }
#undef MFMA_BLOCK

    // epilogue: coalesced stores into this split's partial buffer
    float* Cz = C + (size_t)z * M * N;
#pragma unroll
    for (int ni = 0; ni < 4; ++ni) {
        int n = blockN + wn * 64 + ni * 16 + l15;
#pragma unroll
        for (int mi = 0; mi < 4; ++mi) {
            int mb = blockM + wmm * 64 + mi * 16 + q * 4;
#pragma unroll
            for (int r = 0; r < 4; ++r)
                Cz[(size_t)(mb + r) * N + n] = acc[mi][ni][r];
        }
    }
}

// ---------------------------------------------------------------------------
// Final: out = gamma*rsqrt(var+eps)*(Q0+Q1+Q2+Q3 - mean) + beta, N=256 cols.
// ---------------------------------------------------------------------------
__global__ __launch_bounds__(256) void bn_reduce_kernel(
    const float4* __restrict__ Q0, const float4* __restrict__ Q1,
    const float4* __restrict__ Q2, const float4* __restrict__ Q3,
    const float* __restrict__ gamma, const float* __restrict__ beta,
    const float* __restrict__ mean,  const float* __restrict__ var,
    float4* __restrict__ out, int n4)
{
    int i = blockIdx.x * 256 + threadIdx.x;
    if (i >= n4) return;
    float4 a = Q0[i], b = Q1[i], c = Q2[i], d = Q3[i];
    int nb = (i * 4) & 255;
    float4 g  = *(const float4*)(gamma + nb);
    float4 be = *(const float4*)(beta + nb);
    float4 mn = *(const float4*)(mean + nb);
    float4 vr = *(const float4*)(var + nb);
    float4 o;
    o.x = g.x * rsqrtf(vr.x + 1e-5f) * (a.x + b.x + c.x + d.x - mn.x) + be.x;
    o.y = g.y * rsqrtf(vr.y + 1e-5f) * (a.y + b.y + c.y + d.y - mn.y) + be.y;
    o.z = g.z * rsqrtf(vr.z + 1e-5f) * (a.z + b.z + c.z + d.z - mn.z) + be.z;
    o.w = g.w * rsqrtf(vr.w + 1e-5f) * (a.w + b.w + c.w + d.w - mn.w) + be.w;
    out[i] = o;
}

// ---------------------------------------------------------------------------
extern "C" void kernel_launch(void* const* d_in, const int* in_sizes, int n_in,
                              void* d_out, int out_size, void* d_ws, size_t ws_size,
                              hipStream_t stream) {
    const float* x     = (const float*)d_in[0];
    const float* bw0   = (const float*)d_in[2];
    const float* sw0   = (const float*)d_in[3];
    const float* bw1   = (const float*)d_in[5];
    const float* sw1   = (const float*)d_in[6];
    const float* bw2   = (const float*)d_in[8];
    const float* sw2   = (const float*)d_in[9];
    const float* gamma = (const float*)d_in[10];
    const float* beta  = (const float*)d_in[11];
    const float* mean  = (const float*)d_in[12];
    const float* var   = (const float*)d_in[13];

    char* ws = (char*)d_ws;
    ushort_t* W0 = (ushort_t*)(ws);
    ushort_t* W1 = (ushort_t*)(ws + 3145728);
    ushort_t* W2 = (ushort_t*)(ws + 9437184);
    float*    P  = (float*)(ws + 12582912);   // 2 x 16 MB (L0 partials)
    float*    R  = (float*)(ws + 46137344);   // 2 x 16 MB (L1 partials)
    float*    Q  = (float*)(ws + 79691776);   // 4 x  8 MB (L2 partials)
    float*    out = (float*)d_out;

    const size_t MN = (size_t)8192 * 512;     // partial-buffer stride (floats)
    const size_t QN = (size_t)8192 * 256;

    // pack all weights (one dispatch; repacked every call, d_ws is poisoned)
    pack_all_kernel<<<2048, 256, 0, stream>>>(bw0, sw0, W0, bw1, sw1, W1, bw2, sw2, W2);

    // layer 0: fin=256 (16 slabs, 8/split), N=512, SK=2
    {
        dim3 g(64, 4, 2);
        kan_gemm_kernel<false><<<g, 256, 0, stream>>>(x, W0, P, 8192, 256, 512, 8, 0);
    }
    // layer 1: fin=512 (32 slabs, 16/split), N=512, SK=2; input = P0+P1
    {
        dim3 g(64, 4, 2);
        kan_gemm_kernel<true><<<g, 256, 0, stream>>>(P, W1, R, 8192, 512, 512, 16, MN);
    }
    // layer 2: fin=512 (32 slabs, 8/split), N=256, SK=4; input = R0+R1
    {
        dim3 g(64, 2, 4);
        kan_gemm_kernel<true><<<g, 256, 0, stream>>>(R, W2, Q, 8192, 512, 256, 8, MN);
    }
    // BN + split-K reduce -> out
    bn_reduce_kernel<<<2048, 256, 0, stream>>>(
        (const float4*)Q, (const float4*)(Q + QN), (const float4*)(Q + 2 * QN),
        (const float4*)(Q + 3 * QN), gamma, beta, mean, var,
        (float4*)out, 8192 * 256 / 4);
}

// Round 6
// 313.478 us; speedup vs baseline: 1.9839x; 1.9839x over previous
//
#include <hip/hip_runtime.h>
#include <hip/hip_bf16.h>
#include <cstdint>

// KAN MLP: 256->512->512->256, B=8192, cubic B-splines (uniform grid h=0.25,
// knots -1.75..1.75, 11 bases), BN at the end.
//
// Round-6 = round-4 structure (best: 303 us, GEMM verified 0-conflict,
// 842 TF effective = m97 plateau) with dispatch-count and expand-BW fixes:
//  - prep_kernel: all 3 weight packs + L0 expansion in ONE dispatch
//  - expand kernels: 4 elems/thread, float4 loads (vectorize-or-half-BW)
//  - 7 dispatches total (was 11)
//
// Workspace (146,800,640 bytes total -- proven):
//   A   @ 0          : 8192*6144*2 = 100,663,296 (reused all layers)
//   W0  @ 100663296  : 3,145,728
//   W1  @ 103809024  : 6,291,456
//   W2  @ 110100480  : 3,145,728
//   P   @ 113246208  : L0/L1: 2 x 16MB fp32 partials; L2: 4 x 8MB partials

typedef unsigned short ushort_t;
typedef __bf16 bf16x8 __attribute__((ext_vector_type(8)));
typedef float f32x4 __attribute__((ext_vector_type(4)));

__device__ __forceinline__ ushort_t f2bf(float f) {
    __bf16 h = (__bf16)f;  // RNE
    return __builtin_bit_cast(ushort_t, h);
}

// async global->LDS 16B copy; LDS dest must be wave-uniform base + lane*16.
__device__ __forceinline__ void gload_lds16(const void* g, void* lds) {
    __builtin_amdgcn_global_load_lds(
        (const __attribute__((address_space(1))) unsigned int*)(uintptr_t)g,
        (__attribute__((address_space(3))) unsigned int*)(unsigned int)(uintptr_t)lds,
        16, 0, 0);
}

// x -> [gelu, b0..b10] (12 bf16). Direct cardinal cubic B-spline (verified
// rounds 3-5, absmax 0.0078): b(t), a=|t-2|: a<=1: (4-6a^2+3a^3)/6;
// 1<a<2: (2-a)^3/6; else 0.
__device__ __forceinline__ void expand12(float x, ushort_t* o) {
    float x3 = x * x * x;
    float y  = 0.7978845608028654f * (x + 0.044715f * x3);
    float e  = __expf(2.0f * y);
    float th = 1.0f - 2.0f / (e + 1.0f);       // tanh(y)
    o[0] = f2bf(0.5f * x * (1.0f + th));
    float xs = (x + 1.75f) * 4.0f;
#pragma unroll
    for (int j = 0; j < 11; ++j) {
        float t  = xs - (float)j;
        float a  = fabsf(t - 2.0f);
        float p1 = (3.0f * a - 6.0f) * a * a + 4.0f;
        float c  = 2.0f - a;
        float p2 = c * c * c;
        float v  = (a <= 1.0f) ? p1 : fmaxf(p2, 0.0f);
        o[1 + j] = f2bf(v * (1.0f / 6.0f));
    }
}

// ---------------------------------------------------------------------------
// prep: blocks [0,2048) pack W0/W1/W2 (one output row-element each thread:
// W[o][i*12+0]=base, +1..11=spline);  blocks [2048,4096) expand x -> A
// (4 elems/thread, float4 load, 96B store).
// ---------------------------------------------------------------------------
__global__ __launch_bounds__(256) void prep_kernel(
    const float* __restrict__ bw0, const float* __restrict__ sw0, ushort_t* __restrict__ W0,
    const float* __restrict__ bw1, const float* __restrict__ sw1, ushort_t* __restrict__ W1,
    const float* __restrict__ bw2, const float* __restrict__ sw2, ushort_t* __restrict__ W2,
    const float* __restrict__ x, ushort_t* __restrict__ A)
{
    int b = blockIdx.x;
    if (b < 2048) {
        int idx = b * 256 + threadIdx.x;   // [0, 524288)
        const float* bw; const float* sw; ushort_t* W; int local;
        if (idx < 131072)      { bw = bw0; sw = sw0; W = W0; local = idx; }
        else if (idx < 393216) { bw = bw1; sw = sw1; W = W1; local = idx - 131072; }
        else                   { bw = bw2; sw = sw2; W = W2; local = idx - 393216; }
        union { ushort_t us[12]; uint2 v[3]; } pk;
        pk.us[0] = f2bf(bw[local]);
        const float* s = sw + (size_t)local * 11;
#pragma unroll
        for (int k = 0; k < 11; ++k) pk.us[1 + k] = f2bf(s[k]);
        uint2* dst = (uint2*)(W + (size_t)local * 12);
        dst[0] = pk.v[0]; dst[1] = pk.v[1]; dst[2] = pk.v[2];
    } else {
        int idx = (b - 2048) * 256 + threadIdx.x;   // [0, 524288) quads
        float4 h = *(const float4*)(x + 4 * (size_t)idx);
        union { ushort_t us[48]; uint4 v[6]; } pk;
        expand12(h.x, pk.us);
        expand12(h.y, pk.us + 12);
        expand12(h.z, pk.us + 24);
        expand12(h.w, pk.us + 36);
        uint4* dst = (uint4*)(A + (size_t)idx * 48);
#pragma unroll
        for (int j = 0; j < 6; ++j) dst[j] = pk.v[j];
    }
}

// ---------------------------------------------------------------------------
// Expansion: 4 elems/thread, float4 loads; sums two partials (previous
// layer's split-K reduction fused in). 96 B store per thread.
// ---------------------------------------------------------------------------
__global__ __launch_bounds__(256) void expand_kernel(
    const float* __restrict__ X0, const float* __restrict__ X1,
    ushort_t* __restrict__ A, int total4)
{
    int idx = blockIdx.x * 256 + threadIdx.x;
    if (idx >= total4) return;
    float4 h  = *(const float4*)(X0 + 4 * (size_t)idx);
    float4 h2 = *(const float4*)(X1 + 4 * (size_t)idx);
    h.x += h2.x; h.y += h2.y; h.z += h2.z; h.w += h2.w;
    union { ushort_t us[48]; uint4 v[6]; } pk;
    expand12(h.x, pk.us);
    expand12(h.y, pk.us + 12);
    expand12(h.z, pk.us + 24);
    expand12(h.w, pk.us + 36);
    uint4* dst = (uint4*)(A + (size_t)idx * 48);
#pragma unroll
    for (int j = 0; j < 6; ++j) dst[j] = pk.v[j];
}

// ---------------------------------------------------------------------------
// GEMM (round-4 verified, unchanged): C_z[M,N] = A[M,kslice] @ W[N,kslice]^T.
// Tile 128x128, BK=64, 4 waves 2x2, wave 64x64 (4x4 of 16x16x32 MFMA).
// LDS: 128 rows x 8 chunks x 16B per matrix, chunk XOR-swizzled by row&7
// (measured 0 bank conflicts).
//   A frag: lane holds A[m=l15][k=q*8+j]; C/D: D[m=q*4+r][n=l15].
// ---------------------------------------------------------------------------
__global__ __launch_bounds__(256, 2) void gemm_kernel(
    const ushort_t* __restrict__ A,  // M x K
    const ushort_t* __restrict__ W,  // N x K
    float* __restrict__ C,           // split-K partials, z*M*N apart
    int M, int N, int K, int kcps)   // kcps = 64-chunks per split
{
    __shared__ __align__(16) ushort_t As[128 * 64];  // 16 KB
    __shared__ __align__(16) ushort_t Bs[128 * 64];  // 16 KB

    const int t   = threadIdx.x;
    const int l   = t & 63;
    const int w   = t >> 6;
    const int wm  = w >> 1;
    const int wn  = w & 1;
    const int l15 = l & 15;
    const int q   = l >> 4;
    const int blockM = blockIdx.x * 128;
    const int blockN = blockIdx.y * 128;
    const int kb0 = blockIdx.z * kcps, kb1 = kb0 + kcps;
    float* Cz = C + (size_t)blockIdx.z * M * N;

    f32x4 acc[4][4];
#pragma unroll
    for (int i = 0; i < 4; ++i)
#pragma unroll
        for (int j = 0; j < 4; ++j) acc[i][j] = (f32x4){0.f, 0.f, 0.f, 0.f};

    for (int kb = kb0; kb < kb1; ++kb) {
        const int k0 = kb << 6;
#pragma unroll
        for (int it = 0; it < 4; ++it) {
            int s   = it * 256 + t;
            int row = s >> 3, c = s & 7;
            int g   = c ^ (row & 7);
            gload_lds16(A + ((size_t)(blockM + row) * K + k0 + g * 8), &As[s * 8]);
        }
#pragma unroll
        for (int it = 0; it < 4; ++it) {
            int s   = it * 256 + t;
            int row = s >> 3, c = s & 7;
            int g   = c ^ (row & 7);
            gload_lds16(W + ((size_t)(blockN + row) * K + k0 + g * 8), &Bs[s * 8]);
        }
        __syncthreads();

#pragma unroll
        for (int ks = 0; ks < 2; ++ks) {
            const int kc = ks * 4 + q;
            bf16x8 af[4], bf[4];
#pragma unroll
            for (int mi = 0; mi < 4; ++mi) {
                int m  = wm * 64 + mi * 16 + l15;
                int cs = kc ^ (m & 7);
                af[mi] = *(const bf16x8*)&As[(size_t)(m * 8 + cs) * 8];
            }
#pragma unroll
            for (int ni = 0; ni < 4; ++ni) {
                int n  = wn * 64 + ni * 16 + l15;
                int cs = kc ^ (n & 7);
                bf[ni] = *(const bf16x8*)&Bs[(size_t)(n * 8 + cs) * 8];
            }
#pragma unroll
            for (int mi = 0; mi < 4; ++mi)
#pragma unroll
                for (int ni = 0; ni < 4; ++ni)
                    acc[mi][ni] = __builtin_amdgcn_mfma_f32_16x16x32_bf16(
                        af[mi], bf[ni], acc[mi][ni], 0, 0, 0);
        }
        __syncthreads();
    }

#pragma unroll
    for (int ni = 0; ni < 4; ++ni) {
        int n = blockN + wn * 64 + ni * 16 + l15;
#pragma unroll
        for (int mi = 0; mi < 4; ++mi) {
            int mb = blockM + wm * 64 + mi * 16 + q * 4;
#pragma unroll
            for (int r = 0; r < 4; ++r)
                Cz[(size_t)(mb + r) * N + n] = acc[mi][ni][r];
        }
    }
}

// ---------------------------------------------------------------------------
// Final: out = gamma*rsqrt(var+eps)*(Q0+Q1+Q2+Q3 - mean) + beta, N=256 cols.
// ---------------------------------------------------------------------------
__global__ __launch_bounds__(256) void bn_reduce_kernel(
    const float4* __restrict__ Q0, const float4* __restrict__ Q1,
    const float4* __restrict__ Q2, const float4* __restrict__ Q3,
    const float* __restrict__ gamma, const float* __restrict__ beta,
    const float* __restrict__ mean,  const float* __restrict__ var,
    float4* __restrict__ out, int n4)
{
    int i = blockIdx.x * 256 + threadIdx.x;
    if (i >= n4) return;
    float4 a = Q0[i], b = Q1[i], c = Q2[i], d = Q3[i];
    int nb = (i * 4) & 255;
    float4 g  = *(const float4*)(gamma + nb);
    float4 be = *(const float4*)(beta + nb);
    float4 mn = *(const float4*)(mean + nb);
    float4 vr = *(const float4*)(var + nb);
    float4 o;
    o.x = g.x * rsqrtf(vr.x + 1e-5f) * (a.x + b.x + c.x + d.x - mn.x) + be.x;
    o.y = g.y * rsqrtf(vr.y + 1e-5f) * (a.y + b.y + c.y + d.y - mn.y) + be.y;
    o.z = g.z * rsqrtf(vr.z + 1e-5f) * (a.z + b.z + c.z + d.z - mn.z) + be.z;
    o.w = g.w * rsqrtf(vr.w + 1e-5f) * (a.w + b.w + c.w + d.w - mn.w) + be.w;
    out[i] = o;
}

// ---------------------------------------------------------------------------
extern "C" void kernel_launch(void* const* d_in, const int* in_sizes, int n_in,
                              void* d_out, int out_size, void* d_ws, size_t ws_size,
                              hipStream_t stream) {
    const float* x     = (const float*)d_in[0];
    const float* bw0   = (const float*)d_in[2];
    const float* sw0   = (const float*)d_in[3];
    const float* bw1   = (const float*)d_in[5];
    const float* sw1   = (const float*)d_in[6];
    const float* bw2   = (const float*)d_in[8];
    const float* sw2   = (const float*)d_in[9];
    const float* gamma = (const float*)d_in[10];
    const float* beta  = (const float*)d_in[11];
    const float* mean  = (const float*)d_in[12];
    const float* var   = (const float*)d_in[13];

    char* ws = (char*)d_ws;
    ushort_t* Abuf = (ushort_t*)(ws);
    ushort_t* W0   = (ushort_t*)(ws + 100663296);
    ushort_t* W1   = (ushort_t*)(ws + 103809024);
    ushort_t* W2   = (ushort_t*)(ws + 110100480);
    float*    P0   = (float*)(ws + 113246208);   // 16 MB (L0/L1 partials)
    float*    P1   = (float*)(ws + 130023424);   // 16 MB
    float*    Q0   = (float*)(ws + 113246208);   // 8 MB (L2 partials x4)
    float*    Q1   = (float*)(ws + 121634816);
    float*    Q2   = (float*)(ws + 130023424);
    float*    Q3   = (float*)(ws + 138412032);
    float*    out  = (float*)d_out;

    // 1) pack all weights + expand layer-0 input (one dispatch)
    prep_kernel<<<4096, 256, 0, stream>>>(bw0, sw0, W0, bw1, sw1, W1,
                                          bw2, sw2, W2, x, Abuf);
    // 2) layer 0 GEMM: K=3072 (48 chunks, 24/split), N=512, SK=2
    {
        dim3 g(64, 4, 2);
        gemm_kernel<<<g, 256, 0, stream>>>(Abuf, W0, P0, 8192, 512, 3072, 24);
    }
    // 3) expand h1 = P0+P1 -> A
    expand_kernel<<<4096, 256, 0, stream>>>(P0, P1, Abuf, 8192 * 512 / 4);
    // 4) layer 1 GEMM: K=6144 (96 chunks, 48/split), N=512, SK=2
    {
        dim3 g(64, 4, 2);
        gemm_kernel<<<g, 256, 0, stream>>>(Abuf, W1, P0, 8192, 512, 6144, 48);
    }
    // 5) expand h2 = P0+P1 -> A
    expand_kernel<<<4096, 256, 0, stream>>>(P0, P1, Abuf, 8192 * 512 / 4);
    // 6) layer 2 GEMM: K=6144 (96 chunks, 24/split), N=256, SK=4
    {
        dim3 g(64, 2, 4);
        gemm_kernel<<<g, 256, 0, stream>>>(Abuf, W2, Q0, 8192, 256, 6144, 24);
    }
    // 7) BN + split-K reduce -> out
    bn_reduce_kernel<<<2048, 256, 0, stream>>>(
        (const float4*)Q0, (const float4*)Q1, (const float4*)Q2, (const float4*)Q3,
        gamma, beta, mean, var, (float4*)out, 8192 * 256 / 4);
}

// Round 7
// 307.670 us; speedup vs baseline: 2.0213x; 1.0189x over previous
//
#include <hip/hip_runtime.h>
#include <hip/hip_bf16.h>
#include <cstdint>

// KAN MLP: 256->512->512->256, B=8192, cubic B-splines (uniform grid h=0.25,
// knots -1.75..1.75, 11 bases), BN at the end.
//
// Round-7 = round-6 with 4-blocks/CU GEMM occupancy:
//  - split-K doubled (L0/L1: SK=4, L2: SK=8) -> every GEMM grid = 1024
//    blocks = 4 blocks/CU (LDS 4x32=128KB <= 160KB, VGPR 64 -> fits)
//  - partial buffers in bf16 (halves storage so SK=4 fits workspace;
//    halves partial r/w traffic). GEMM core untouched (verified 0-conflict).
//
// Workspace (145,227,776 bytes <= 146,800,640 proven):
//   A   @ 0          : 8192*6144*2 = 100,663,296 (reused all layers)
//   W0  @ 100663296  : 3,145,728
//   W1  @ 103809024  : 6,291,456
//   W2  @ 110100480  : 3,145,728
//   P   @ 113246208  : 32 MB partial region:
//                      L0/L1: 4 x 8 MB bf16 (stride 8192*512)
//                      L2   : 8 x 4 MB bf16 (stride 8192*256)

typedef unsigned short ushort_t;
typedef __bf16 bf16x8 __attribute__((ext_vector_type(8)));
typedef float f32x4 __attribute__((ext_vector_type(4)));

__device__ __forceinline__ ushort_t f2bf(float f) {
    __bf16 h = (__bf16)f;  // RNE
    return __builtin_bit_cast(ushort_t, h);
}
__device__ __forceinline__ float bf2f(ushort_t u) {
    unsigned int v = ((unsigned int)u) << 16;
    return __builtin_bit_cast(float, v);
}

// async global->LDS 16B copy; LDS dest must be wave-uniform base + lane*16.
__device__ __forceinline__ void gload_lds16(const void* g, void* lds) {
    __builtin_amdgcn_global_load_lds(
        (const __attribute__((address_space(1))) unsigned int*)(uintptr_t)g,
        (__attribute__((address_space(3))) unsigned int*)(unsigned int)(uintptr_t)lds,
        16, 0, 0);
}

// x -> [gelu, b0..b10] (12 bf16). Direct cardinal cubic B-spline (verified
// rounds 3-6, absmax 0.0078): b(t), a=|t-2|: a<=1: (4-6a^2+3a^3)/6;
// 1<a<2: (2-a)^3/6; else 0.
__device__ __forceinline__ void expand12(float x, ushort_t* o) {
    float x3 = x * x * x;
    float y  = 0.7978845608028654f * (x + 0.044715f * x3);
    float e  = __expf(2.0f * y);
    float th = 1.0f - 2.0f / (e + 1.0f);       // tanh(y)
    o[0] = f2bf(0.5f * x * (1.0f + th));
    float xs = (x + 1.75f) * 4.0f;
#pragma unroll
    for (int j = 0; j < 11; ++j) {
        float t  = xs - (float)j;
        float a  = fabsf(t - 2.0f);
        float p1 = (3.0f * a - 6.0f) * a * a + 4.0f;
        float c  = 2.0f - a;
        float p2 = c * c * c;
        float v  = (a <= 1.0f) ? p1 : fmaxf(p2, 0.0f);
        o[1 + j] = f2bf(v * (1.0f / 6.0f));
    }
}

// ---------------------------------------------------------------------------
// prep: blocks [0,2048) pack W0/W1/W2; blocks [2048,4096) expand x -> A
// (4 elems/thread, float4 load).
// ---------------------------------------------------------------------------
__global__ __launch_bounds__(256) void prep_kernel(
    const float* __restrict__ bw0, const float* __restrict__ sw0, ushort_t* __restrict__ W0,
    const float* __restrict__ bw1, const float* __restrict__ sw1, ushort_t* __restrict__ W1,
    const float* __restrict__ bw2, const float* __restrict__ sw2, ushort_t* __restrict__ W2,
    const float* __restrict__ x, ushort_t* __restrict__ A)
{
    int b = blockIdx.x;
    if (b < 2048) {
        int idx = b * 256 + threadIdx.x;   // [0, 524288)
        const float* bw; const float* sw; ushort_t* W; int local;
        if (idx < 131072)      { bw = bw0; sw = sw0; W = W0; local = idx; }
        else if (idx < 393216) { bw = bw1; sw = sw1; W = W1; local = idx - 131072; }
        else                   { bw = bw2; sw = sw2; W = W2; local = idx - 393216; }
        union { ushort_t us[12]; uint2 v[3]; } pk;
        pk.us[0] = f2bf(bw[local]);
        const float* s = sw + (size_t)local * 11;
#pragma unroll
        for (int k = 0; k < 11; ++k) pk.us[1 + k] = f2bf(s[k]);
        uint2* dst = (uint2*)(W + (size_t)local * 12);
        dst[0] = pk.v[0]; dst[1] = pk.v[1]; dst[2] = pk.v[2];
    } else {
        int idx = (b - 2048) * 256 + threadIdx.x;   // [0, 524288) quads
        float4 h = *(const float4*)(x + 4 * (size_t)idx);
        union { ushort_t us[48]; uint4 v[6]; } pk;
        expand12(h.x, pk.us);
        expand12(h.y, pk.us + 12);
        expand12(h.z, pk.us + 24);
        expand12(h.w, pk.us + 36);
        uint4* dst = (uint4*)(A + (size_t)idx * 48);
#pragma unroll
        for (int j = 0; j < 6; ++j) dst[j] = pk.v[j];
    }
}

// ---------------------------------------------------------------------------
// Expansion: h = sum of 4 bf16 partial streams; 4 elems/thread.
// ---------------------------------------------------------------------------
__global__ __launch_bounds__(256) void expand_kernel(
    const ushort_t* __restrict__ P, size_t stride,   // 4 partials, 'stride' els apart
    ushort_t* __restrict__ A, int total4)
{
    int idx = blockIdx.x * 256 + threadIdx.x;
    if (idx >= total4) return;
    float h[4] = {0.f, 0.f, 0.f, 0.f};
#pragma unroll
    for (int z = 0; z < 4; ++z) {
        ushort4 p = *(const ushort4*)(P + z * stride + 4 * (size_t)idx);
        h[0] += bf2f(p.x); h[1] += bf2f(p.y); h[2] += bf2f(p.z); h[3] += bf2f(p.w);
    }
    union { ushort_t us[48]; uint4 v[6]; } pk;
    expand12(h[0], pk.us);
    expand12(h[1], pk.us + 12);
    expand12(h[2], pk.us + 24);
    expand12(h[3], pk.us + 36);
    uint4* dst = (uint4*)(A + (size_t)idx * 48);
#pragma unroll
    for (int j = 0; j < 6; ++j) dst[j] = pk.v[j];
}

// ---------------------------------------------------------------------------
// GEMM (round-4/6 verified core, unchanged): C_z = A[M,ksl] @ W[N,ksl]^T.
// Tile 128x128, BK=64, 4 waves 2x2, wave 64x64 (4x4 of 16x16x32 MFMA).
// LDS: 128 rows x 8 chunks x 16B per matrix, chunk XOR-swizzled by row&7
// (measured 0 bank conflicts). Epilogue now stores bf16 partials.
//   A frag: lane holds A[m=l15][k=q*8+j]; C/D: D[m=q*4+r][n=l15].
// ---------------------------------------------------------------------------
__global__ __launch_bounds__(256, 2) void gemm_kernel(
    const ushort_t* __restrict__ A,  // M x K
    const ushort_t* __restrict__ W,  // N x K
    ushort_t* __restrict__ C,        // split-K bf16 partials, z*M*N apart
    int M, int N, int K, int kcps)   // kcps = 64-chunks per split
{
    __shared__ __align__(16) ushort_t As[128 * 64];  // 16 KB
    __shared__ __align__(16) ushort_t Bs[128 * 64];  // 16 KB

    const int t   = threadIdx.x;
    const int l   = t & 63;
    const int w   = t >> 6;
    const int wm  = w >> 1;
    const int wn  = w & 1;
    const int l15 = l & 15;
    const int q   = l >> 4;
    const int blockM = blockIdx.x * 128;
    const int blockN = blockIdx.y * 128;
    const int kb0 = blockIdx.z * kcps, kb1 = kb0 + kcps;
    ushort_t* Cz = C + (size_t)blockIdx.z * M * N;

    f32x4 acc[4][4];
#pragma unroll
    for (int i = 0; i < 4; ++i)
#pragma unroll
        for (int j = 0; j < 4; ++j) acc[i][j] = (f32x4){0.f, 0.f, 0.f, 0.f};

    for (int kb = kb0; kb < kb1; ++kb) {
        const int k0 = kb << 6;
#pragma unroll
        for (int it = 0; it < 4; ++it) {
            int s   = it * 256 + t;
            int row = s >> 3, c = s & 7;
            int g   = c ^ (row & 7);
            gload_lds16(A + ((size_t)(blockM + row) * K + k0 + g * 8), &As[s * 8]);
        }
#pragma unroll
        for (int it = 0; it < 4; ++it) {
            int s   = it * 256 + t;
            int row = s >> 3, c = s & 7;
            int g   = c ^ (row & 7);
            gload_lds16(W + ((size_t)(blockN + row) * K + k0 + g * 8), &Bs[s * 8]);
        }
        __syncthreads();

#pragma unroll
        for (int ks = 0; ks < 2; ++ks) {
            const int kc = ks * 4 + q;
            bf16x8 af[4], bf[4];
#pragma unroll
            for (int mi = 0; mi < 4; ++mi) {
                int m  = wm * 64 + mi * 16 + l15;
                int cs = kc ^ (m & 7);
                af[mi] = *(const bf16x8*)&As[(size_t)(m * 8 + cs) * 8];
            }
#pragma unroll
            for (int ni = 0; ni < 4; ++ni) {
                int n  = wn * 64 + ni * 16 + l15;
                int cs = kc ^ (n & 7);
                bf[ni] = *(const bf16x8*)&Bs[(size_t)(n * 8 + cs) * 8];
            }
#pragma unroll
            for (int mi = 0; mi < 4; ++mi)
#pragma unroll
                for (int ni = 0; ni < 4; ++ni)
                    acc[mi][ni] = __builtin_amdgcn_mfma_f32_16x16x32_bf16(
                        af[mi], bf[ni], acc[mi][ni], 0, 0, 0);
        }
        __syncthreads();
    }

    // epilogue: bf16 partial stores (16 lanes x 2B = 32B segments)
#pragma unroll
    for (int ni = 0; ni < 4; ++ni) {
        int n = blockN + wn * 64 + ni * 16 + l15;
#pragma unroll
        for (int mi = 0; mi < 4; ++mi) {
            int mb = blockM + wm * 64 + mi * 16 + q * 4;
#pragma unroll
            for (int r = 0; r < 4; ++r)
                Cz[(size_t)(mb + r) * N + n] = f2bf(acc[mi][ni][r]);
        }
    }
}

// ---------------------------------------------------------------------------
// Final: out = gamma*rsqrt(var+eps)*(sum of 8 bf16 partials - mean) + beta.
// ---------------------------------------------------------------------------
__global__ __launch_bounds__(256) void bn_reduce_kernel(
    const ushort_t* __restrict__ P, size_t stride,   // 8 partials
    const float* __restrict__ gamma, const float* __restrict__ beta,
    const float* __restrict__ mean,  const float* __restrict__ var,
    float4* __restrict__ out, int n4)
{
    int i = blockIdx.x * 256 + threadIdx.x;
    if (i >= n4) return;
    float h[4] = {0.f, 0.f, 0.f, 0.f};
#pragma unroll
    for (int z = 0; z < 8; ++z) {
        ushort4 p = *(const ushort4*)(P + z * stride + 4 * (size_t)i);
        h[0] += bf2f(p.x); h[1] += bf2f(p.y); h[2] += bf2f(p.z); h[3] += bf2f(p.w);
    }
    int nb = (i * 4) & 255;
    float4 g  = *(const float4*)(gamma + nb);
    float4 be = *(const float4*)(beta + nb);
    float4 mn = *(const float4*)(mean + nb);
    float4 vr = *(const float4*)(var + nb);
    float4 o;
    o.x = g.x * rsqrtf(vr.x + 1e-5f) * (h[0] - mn.x) + be.x;
    o.y = g.y * rsqrtf(vr.y + 1e-5f) * (h[1] - mn.y) + be.y;
    o.z = g.z * rsqrtf(vr.z + 1e-5f) * (h[2] - mn.z) + be.z;
    o.w = g.w * rsqrtf(vr.w + 1e-5f) * (h[3] - mn.w) + be.w;
    out[i] = o;
}

// ---------------------------------------------------------------------------
extern "C" void kernel_launch(void* const* d_in, const int* in_sizes, int n_in,
                              void* d_out, int out_size, void* d_ws, size_t ws_size,
                              hipStream_t stream) {
    const float* x     = (const float*)d_in[0];
    const float* bw0   = (const float*)d_in[2];
    const float* sw0   = (const float*)d_in[3];
    const float* bw1   = (const float*)d_in[5];
    const float* sw1   = (const float*)d_in[6];
    const float* bw2   = (const float*)d_in[8];
    const float* sw2   = (const float*)d_in[9];
    const float* gamma = (const float*)d_in[10];
    const float* beta  = (const float*)d_in[11];
    const float* mean  = (const float*)d_in[12];
    const float* var   = (const float*)d_in[13];

    char* ws = (char*)d_ws;
    ushort_t* Abuf = (ushort_t*)(ws);
    ushort_t* W0   = (ushort_t*)(ws + 100663296);
    ushort_t* W1   = (ushort_t*)(ws + 103809024);
    ushort_t* W2   = (ushort_t*)(ws + 110100480);
    ushort_t* P    = (ushort_t*)(ws + 113246208);  // 32 MB bf16 partial region
    float*    out  = (float*)d_out;

    const size_t PS = (size_t)8192 * 512;   // L0/L1 partial stride (elements)
    const size_t QS = (size_t)8192 * 256;   // L2 partial stride

    // 1) pack all weights + expand layer-0 input
    prep_kernel<<<4096, 256, 0, stream>>>(bw0, sw0, W0, bw1, sw1, W1,
                                          bw2, sw2, W2, x, Abuf);
    // 2) layer 0 GEMM: K=3072 (48 chunks, 12/split), N=512, SK=4
    {
        dim3 g(64, 4, 4);
        gemm_kernel<<<g, 256, 0, stream>>>(Abuf, W0, P, 8192, 512, 3072, 12);
    }
    // 3) expand h1 = sum(P[0..3]) -> A
    expand_kernel<<<4096, 256, 0, stream>>>(P, PS, Abuf, 8192 * 512 / 4);
    // 4) layer 1 GEMM: K=6144 (96 chunks, 24/split), N=512, SK=4
    {
        dim3 g(64, 4, 4);
        gemm_kernel<<<g, 256, 0, stream>>>(Abuf, W1, P, 8192, 512, 6144, 24);
    }
    // 5) expand h2 = sum(P[0..3]) -> A
    expand_kernel<<<4096, 256, 0, stream>>>(P, PS, Abuf, 8192 * 512 / 4);
    // 6) layer 2 GEMM: K=6144 (96 chunks, 12/split), N=256, SK=8
    {
        dim3 g(64, 2, 8);
        gemm_kernel<<<g, 256, 0, stream>>>(Abuf, W2, P, 8192, 256, 6144, 12);
    }
    // 7) BN + 8-way split-K reduce -> out
    bn_reduce_kernel<<<2048, 256, 0, stream>>>(P, QS, gamma, beta, mean, var,
                                               (float4*)out, 8192 * 256 / 4);
}